// Round 15
// baseline (342.047 us; speedup 1.0000x reference)
//
#include <hip/hip_runtime.h>

#define NN 16
constexpr int BB = 32, CIN = 64, HH = 112, WW = 112;
constexpr int HWC = HH * WW;          // 12544
constexpr int COUT = 128, HW2 = 56 * 56;
constexpr int NE = 64;
constexpr int QPP = HWC / 4;          // 3136 quads per plane
constexpr int PLB = 2;                // planes per conv block
constexpr int CBI = CIN / PLB;        // 32 conv blocks per image
constexpr int QPB2 = PLB * QPP;       // 6272 quads per block
constexpr int ITER = 25;              // ceil(6272/256)
constexpr int PPI = CBI;              // 32 partials per image
constexpr int PF4 = COUT * HW2 / 4;   // 100352 float4 per batch
constexpr int SBPB = 28;              // scale blocks per batch (28*3584 = PF4)
constexpr int JPT = 14;               // float4 iters per scale thread
constexpr int PREF = 6;               // register prefetch depth

// ---- Kernel 1: fill-pattern 1x1 conv + direct atomic segment scatter ----
// Block = (image b, plane-pair cg). The block walks its 100KB slab EXACTLY
// like a fill: idx = it*256+tid -> unit stride across lanes, sequential
// across iterations. No per-thread accumulator (R8's VGPR killer): each
// loaded quad is scattered immediately via 4 LDS atomics into the 8-replica
// skewed accumulator (~2-way conflicts = free). seg re-read per plane is
// L2-hot. Block cg==0 contributes row/col/cnt during its cl==0 plane.
__global__ __launch_bounds__(256) void k_conv_seg(
    const float* __restrict__ Bfor, const int* __restrict__ seg,
    const float* __restrict__ convw, float* __restrict__ part)
{
    __shared__ float acc8[8 * 80];      // [replica][node*5+st], bank-skewed
    const int tid = threadIdx.x;
    const int bid = blockIdx.x;
    const int b   = bid >> 5;           // image
    const int cg  = bid & 31;           // plane-pair
    const int c0  = cg * PLB;

    for (int i = tid; i < 8 * 80; i += 256) acc8[i] = 0.f;
    __syncthreads();

    const float w0 = convw[c0];
    const float w1 = convw[c0 + 1];
    const float* base = Bfor + (size_t)(b * CIN + c0) * HWC;
    const int*   segb = seg + (size_t)b * HWC;
    const int rep = tid & 7;
    float* ar = &acc8[rep * 80];
    const bool blk0 = (cg == 0);

    #pragma unroll 5
    for (int it = 0; it < ITER; ++it) {
        const int idx = it * 256 + tid;             // quad index in slab
        if (idx < QPB2) {
            const int cl = idx / QPP;               // 0 or 1 (local plane)
            const int q  = idx - cl * QPP;          // quad within plane
            const float wc = cl ? w1 : w0;
            const float4 v = *reinterpret_cast<const float4*>(base + (size_t)idx * 4);
            const int4  sg = *reinterpret_cast<const int4*>(segb + q * 4);
            atomicAdd(ar + sg.x * 5 + 2, v.x * wc);
            atomicAdd(ar + sg.y * 5 + 2, v.y * wc);
            atomicAdd(ar + sg.z * 5 + 2, v.z * wc);
            atomicAdd(ar + sg.w * 5 + 2, v.w * wc);
            if (blk0 && cl == 0) {                  // once per pixel per image
                const int p = q * 4;
                const float row  = (float)(p / WW); // WW%4==0 -> same row x4
                const float col0 = (float)(p % WW);
                atomicAdd(ar + sg.x * 5 + 0, row);
                atomicAdd(ar + sg.y * 5 + 0, row);
                atomicAdd(ar + sg.z * 5 + 0, row);
                atomicAdd(ar + sg.w * 5 + 0, row);
                atomicAdd(ar + sg.x * 5 + 1, col0);
                atomicAdd(ar + sg.y * 5 + 1, col0 + 1.f);
                atomicAdd(ar + sg.z * 5 + 1, col0 + 2.f);
                atomicAdd(ar + sg.w * 5 + 1, col0 + 3.f);
                atomicAdd(ar + sg.x * 5 + 3, 1.f);
                atomicAdd(ar + sg.y * 5 + 3, 1.f);
                atomicAdd(ar + sg.z * 5 + 3, 1.f);
                atomicAdd(ar + sg.w * 5 + 3, 1.f);
            }
        }
    }
    __syncthreads();

    if (tid < 64) {
        const int node = tid >> 2, st = tid & 3;
        float v = 0.f;
        #pragma unroll
        for (int r = 0; r < 8; ++r) v += acc8[r * 80 + node * 5 + st];
        part[(size_t)bid * 64 + tid] = v;   // bid == b*32+cg
    }
}

// ------- Kernel 2: fused graph stage + scale (R9 verbatim; 32 partials) ----
__global__ __launch_bounds__(256) void k_graph_scale(
    const float* __restrict__ part, const int* __restrict__ src,
    const int* __restrict__ dst,  const float* __restrict__ convb,
    const float* __restrict__ W1, const float* __restrict__ b1,
    const float* __restrict__ W2, const float* __restrict__ b2,
    const float* __restrict__ fcw, const float* __restrict__ fcb,
    const float* __restrict__ Bfon, float* __restrict__ out)
{
    const int b    = blockIdx.x / SBPB;
    const int blkb = blockIdx.x % SBPB;
    const int tid  = threadIdx.x;
    const int w0   = blkb * (JPT * 256);   // contiguous window in [0, PF4)

    __shared__ float X[NN][4];
    __shared__ float A[NN][NN];
    __shared__ float nrm[NN];
    __shared__ float h1s[NN][32];
    __shared__ float agg[NN][32];
    __shared__ float pred[4][64];
    __shared__ float gpart[2][COUT];
    __shared__ float Gs[COUT];

    const float4* bf4 = reinterpret_cast<const float4*>(Bfon) + (size_t)b * PF4;
    float4*       ob4 = reinterpret_cast<float4*>(out)        + (size_t)b * PF4;

    // ---- issue Bfon prefetch (depth PREF) before Phase A ----
    float4 r[JPT];
    #pragma unroll
    for (int j = 0; j < PREF; ++j) r[j] = bf4[w0 + j * 256 + tid];

    // ---- Phase A: tiny graph network (redundant across SBPB blocks) ----
    {   // reduce 32 partials: 4 chunks x 8, coalesced
        const int id = tid & 63, chunk = tid >> 6;
        float v = 0.f;
        #pragma unroll
        for (int j = 0; j < 8; ++j)
            v += part[(size_t)(b * PPI + chunk * 8 + j) * 64 + id];
        pred[chunk][id] = v;
    }
    for (int i = tid; i < NN * NN; i += 256) ((float*)A)[i] = 0.f;
    __syncthreads();

    if (tid < 64) {
        const int node = tid >> 2, st = tid & 3;
        X[node][st] = pred[0][tid] + pred[1][tid] + pred[2][tid] + pred[3][tid];
    }
    __syncthreads();

    if (tid < NN) {        // raw sums -> features (conv bias folded in)
        const float cnt = X[tid][3];
        const float cs  = fmaxf(cnt, 1.f);
        X[tid][0] = X[tid][0] / cs;
        X[tid][1] = X[tid][1] / cs;
        X[tid][2] = (X[tid][2] + cnt * convb[0]) / cs;
    }
    __syncthreads();

    // normalize feature cols 2,3 across nodes (mean, std ddof=1)
    if (tid < 2) {
        const int c = 2 + tid;
        float mu = 0.f;
        for (int i = 0; i < NN; ++i) mu += X[i][c];
        mu *= (1.f / NN);
        float var = 0.f;
        for (int i = 0; i < NN; ++i) { const float d = X[i][c] - mu; var = fmaf(d, d, var); }
        var *= (1.f / (NN - 1));
        const float inv = 1.f / (sqrtf(var) + 1.f);
        for (int i = 0; i < NN; ++i) X[i][c] = (X[i][c] - mu) * inv;
    }
    // build adjacency (idempotent set-to-1)
    if (tid >= 64 && tid < 64 + NE) {
        const int e = tid - 64;
        const int s = src[b * NE + e], d = dst[b * NE + e];
        A[s][d] = 1.f;
        A[d][s] = 1.f;
    }
    __syncthreads();

    if (tid < NN) {
        float rs = 0.f;
        for (int j = 0; j < NN; ++j) rs += A[tid][j];
        nrm[tid] = 1.f / sqrtf(fmaxf(rs, 1.f));
    }
    __syncthreads();

    if (tid < NN * 4) {    // agg1 (16x4)
        const int i = tid >> 2, k = tid & 3;
        float s = 0.f;
        for (int j = 0; j < NN; ++j) s = fmaf(A[i][j] * nrm[j], X[j][k], s);
        agg[i][k] = s;
    }
    __syncthreads();

    for (int t = tid; t < NN * 32; t += 256) {   // h1 (16x32)
        const int i = t >> 5, f = t & 31;
        float s = 0.f;
        #pragma unroll
        for (int k = 0; k < 4; ++k) s = fmaf(agg[i][k], W1[k * 32 + f], s);
        h1s[i][f] = fmaxf(fmaf(nrm[i], s, b1[f]), 0.f);
    }
    __syncthreads();

    for (int t = tid; t < NN * 32; t += 256) {   // agg2 (16x32)
        const int i = t >> 5, k = t & 31;
        float s = 0.f;
        for (int j = 0; j < NN; ++j) s = fmaf(A[i][j] * nrm[j], h1s[j][k], s);
        agg[i][k] = s;
    }
    __syncthreads();

    {   // h2 + FC, i-range split across 2 half-blocks
        const int f = tid & 127, half = tid >> 7;
        float g = 0.f;
        const float bf = b2[f];
        for (int i = half * 8; i < half * 8 + 8; ++i) {
            float s = 0.f;
            #pragma unroll
            for (int k = 0; k < 32; ++k) s = fmaf(agg[i][k], W2[k * COUT + f], s);
            g = fmaf(fcw[i], fmaxf(fmaf(nrm[i], s, bf), 0.f), g);
        }
        gpart[half][f] = g;
    }
    __syncthreads();
    if (tid < COUT) Gs[tid] = gpart[0][tid] + gpart[1][tid] + fcb[0];
    __syncthreads();

    // ---- Phase B: rolling register pipeline over the contiguous window ----
    #pragma unroll
    for (int j = 0; j < JPT; ++j) {
        if (j + PREF < JPT) r[j + PREF] = bf4[w0 + (j + PREF) * 256 + tid];
        const int t = w0 + j * 256 + tid;
        const float g = Gs[t / (HW2 / 4)];   // 784 float4 per (b,c) plane
        ob4[t] = make_float4(r[j].x * g, r[j].y * g, r[j].z * g, r[j].w * g);
    }
}

extern "C" void kernel_launch(void* const* d_in, const int* in_sizes, int n_in,
                              void* d_out, int out_size, void* d_ws, size_t ws_size,
                              hipStream_t stream)
{
    const float* Bfor  = (const float*)d_in[0];
    const float* Bfon  = (const float*)d_in[1];
    const int*   seg   = (const int*)d_in[2];
    const int*   src   = (const int*)d_in[3];
    const int*   dst   = (const int*)d_in[4];
    const float* convw = (const float*)d_in[5];
    const float* convb = (const float*)d_in[6];
    const float* W1    = (const float*)d_in[7];
    const float* b1    = (const float*)d_in[8];
    const float* W2    = (const float*)d_in[9];
    const float* b2    = (const float*)d_in[10];
    const float* fcw   = (const float*)d_in[11];
    const float* fcb   = (const float*)d_in[12];

    float* part = (float*)d_ws;           // 1024 * 64 floats = 256 KB
    float* out  = (float*)d_out;

    k_conv_seg<<<BB * CBI, 256, 0, stream>>>(Bfor, seg, convw, part);
    k_graph_scale<<<BB * SBPB, 256, 0, stream>>>(part, src, dst, convb,
                                                 W1, b1, W2, b2, fcw, fcb,
                                                 Bfon, out);
}

// Round 16
// 47.813 us; speedup vs baseline: 7.1539x; 7.1539x over previous
//
#include <hip/hip_runtime.h>

#define NN 16
constexpr int BB = 32, CIN = 64, HH = 112, WW = 112;
constexpr int HWC = HH * WW;          // 12544
constexpr int COUT = 128, HW2 = 56 * 56;
constexpr int NE = 64;
constexpr int NQ = HWC / 4;           // 3136 float4 pixels per image
constexpr int QPB = 64;               // pixel-quads per conv block
constexpr int BPI = NQ / QPB;         // 49 conv blocks per image (exact)
constexpr int PF4 = COUT * HW2 / 4;   // 100352 float4 per batch
constexpr int SBPB = 28;              // scale blocks per batch (28*3584 = PF4)
constexpr int JPT = 14;               // float4 iters per k2 thread (14*256=3584)
constexpr int PREF = 6;               // register prefetch depth

// ---------------- Kernel 1: 1x1 conv (channel-split) + segment scatter -----
// (R3/R9 version verbatim — empirical optimum across 6 structural variants.)
__global__ __launch_bounds__(256) void k_conv_seg(
    const float* __restrict__ Bfor, const int* __restrict__ seg,
    const float* __restrict__ convw, float* __restrict__ part)
{
    __shared__ float w[CIN];
    __shared__ float ps[4 * QPB * 5];   // [cg][quad][px], px stride 5 (bank skew)
    __shared__ float acc[8 * 80];       // [replica][node*5+st], skewed banks
    const int tid = threadIdx.x;
    const int b   = blockIdx.x / BPI;
    const int blk = blockIdx.x % BPI;
    const int cg  = tid >> 6;           // channel group == wave id
    const int l   = tid & 63;           // quad lane

    if (tid < CIN) w[tid] = convw[tid];
    for (int i = tid; i < 8 * 80; i += 256) acc[i] = 0.f;
    __syncthreads();

    const int q = blk * QPB + l;        // < 3136 always (exact tiling)
    const int p = q * 4;
    const float* base = Bfor + (size_t)b * CIN * HWC + (size_t)(cg * 16) * HWC + p;

    float4 s = make_float4(0.f, 0.f, 0.f, 0.f);
    #pragma unroll
    for (int cc = 0; cc < 16; ++cc) {
        const float4 v = *reinterpret_cast<const float4*>(base + (size_t)cc * HWC);
        const float wc = w[cg * 16 + cc];
        s.x = fmaf(v.x, wc, s.x);
        s.y = fmaf(v.y, wc, s.y);
        s.z = fmaf(v.z, wc, s.z);
        s.w = fmaf(v.w, wc, s.w);
    }
    ps[cg * 320 + l * 5 + 0] = s.x;
    ps[cg * 320 + l * 5 + 1] = s.y;
    ps[cg * 320 + l * 5 + 2] = s.z;
    ps[cg * 320 + l * 5 + 3] = s.w;
    __syncthreads();

    if (tid < 64) {
        float r0 = 0.f, r1 = 0.f, r2 = 0.f, r3 = 0.f;
        #pragma unroll
        for (int g = 0; g < 4; ++g) {
            r0 += ps[g * 320 + tid * 5 + 0];
            r1 += ps[g * 320 + tid * 5 + 1];
            r2 += ps[g * 320 + tid * 5 + 2];
            r3 += ps[g * 320 + tid * 5 + 3];
        }
        const int pp = (blk * QPB + tid) * 4;
        const int4 sg = *reinterpret_cast<const int4*>(seg + (size_t)b * HWC + pp);
        const float row  = (float)(pp / WW);   // WW%4==0 -> all 4 px same row
        const float col0 = (float)(pp % WW);
        const int k = tid & 7;                 // replica
        atomicAdd(&acc[k * 80 + sg.x * 5 + 0], row);
        atomicAdd(&acc[k * 80 + sg.x * 5 + 1], col0);
        atomicAdd(&acc[k * 80 + sg.x * 5 + 2], r0);
        atomicAdd(&acc[k * 80 + sg.x * 5 + 3], 1.f);
        atomicAdd(&acc[k * 80 + sg.y * 5 + 0], row);
        atomicAdd(&acc[k * 80 + sg.y * 5 + 1], col0 + 1.f);
        atomicAdd(&acc[k * 80 + sg.y * 5 + 2], r1);
        atomicAdd(&acc[k * 80 + sg.y * 5 + 3], 1.f);
        atomicAdd(&acc[k * 80 + sg.z * 5 + 0], row);
        atomicAdd(&acc[k * 80 + sg.z * 5 + 1], col0 + 2.f);
        atomicAdd(&acc[k * 80 + sg.z * 5 + 2], r2);
        atomicAdd(&acc[k * 80 + sg.z * 5 + 3], 1.f);
        atomicAdd(&acc[k * 80 + sg.w * 5 + 0], row);
        atomicAdd(&acc[k * 80 + sg.w * 5 + 1], col0 + 3.f);
        atomicAdd(&acc[k * 80 + sg.w * 5 + 2], r3);
        atomicAdd(&acc[k * 80 + sg.w * 5 + 3], 1.f);
    }
    __syncthreads();

    if (tid < NN * 4) {
        const int node = tid >> 2, st = tid & 3;
        float v = 0.f;
        #pragma unroll
        for (int k = 0; k < 8; ++k) v += acc[k * 80 + node * 5 + st];
        part[((b * BPI + blk) * NN + node) * 4 + st] = v;
    }
}

// ------- Kernel 2: fused graph stage + scale, with Bfon register prefetch
// issued BEFORE Phase A so HBM streams during the graph-network bubble.
__global__ __launch_bounds__(256) void k_graph_scale(
    const float* __restrict__ part, const int* __restrict__ src,
    const int* __restrict__ dst,  const float* __restrict__ convb,
    const float* __restrict__ W1, const float* __restrict__ b1,
    const float* __restrict__ W2, const float* __restrict__ b2,
    const float* __restrict__ fcw, const float* __restrict__ fcb,
    const float* __restrict__ Bfon, float* __restrict__ out)
{
    const int b    = blockIdx.x / SBPB;
    const int blkb = blockIdx.x % SBPB;
    const int tid  = threadIdx.x;
    const int w0   = blkb * (JPT * 256);   // contiguous window in [0, PF4)

    __shared__ float X[NN][4];
    __shared__ float A[NN][NN];
    __shared__ float nrm[NN];
    __shared__ float h1s[NN][32];
    __shared__ float agg[NN][32];
    __shared__ float gpart[2][COUT];
    __shared__ float Gs[COUT];

    const float4* bf4 = reinterpret_cast<const float4*>(Bfon) + (size_t)b * PF4;
    float4*       ob4 = reinterpret_cast<float4*>(out)        + (size_t)b * PF4;

    // ---- issue Bfon prefetch (depth PREF) before Phase A ----
    float4 r[JPT];
    #pragma unroll
    for (int j = 0; j < PREF; ++j) r[j] = bf4[w0 + j * 256 + tid];

    // ---- Phase A: tiny graph network (redundant across SBPB blocks) ----
    if (tid < 64) {        // reduce 49 conv-block partials, coalesced per iter
        const int node = tid >> 2, st = tid & 3;
        float v = 0.f;
        for (int k = 0; k < BPI; ++k) v += part[((b * BPI + k) * NN + node) * 4 + st];
        X[node][st] = v;
    }
    for (int i = tid; i < NN * NN; i += 256) ((float*)A)[i] = 0.f;
    __syncthreads();

    if (tid < NN) {        // raw sums -> features (conv bias folded in)
        const float cnt = X[tid][3];
        const float cs  = fmaxf(cnt, 1.f);
        X[tid][0] = X[tid][0] / cs;
        X[tid][1] = X[tid][1] / cs;
        X[tid][2] = (X[tid][2] + cnt * convb[0]) / cs;
    }
    __syncthreads();

    // normalize feature cols 2,3 across nodes (mean, std ddof=1)
    if (tid < 2) {
        const int c = 2 + tid;
        float mu = 0.f;
        for (int i = 0; i < NN; ++i) mu += X[i][c];
        mu *= (1.f / NN);
        float var = 0.f;
        for (int i = 0; i < NN; ++i) { const float d = X[i][c] - mu; var = fmaf(d, d, var); }
        var *= (1.f / (NN - 1));
        const float inv = 1.f / (sqrtf(var) + 1.f);
        for (int i = 0; i < NN; ++i) X[i][c] = (X[i][c] - mu) * inv;
    }
    // build adjacency (idempotent set-to-1)
    if (tid >= 64 && tid < 64 + NE) {
        const int e = tid - 64;
        const int s = src[b * NE + e], d = dst[b * NE + e];
        A[s][d] = 1.f;
        A[d][s] = 1.f;
    }
    __syncthreads();

    if (tid < NN) {
        float rs = 0.f;
        for (int j = 0; j < NN; ++j) rs += A[tid][j];
        nrm[tid] = 1.f / sqrtf(fmaxf(rs, 1.f));
    }
    __syncthreads();

    if (tid < NN * 4) {    // agg1 (16x4)
        const int i = tid >> 2, k = tid & 3;
        float s = 0.f;
        for (int j = 0; j < NN; ++j) s = fmaf(A[i][j] * nrm[j], X[j][k], s);
        agg[i][k] = s;
    }
    __syncthreads();

    for (int t = tid; t < NN * 32; t += 256) {   // h1 (16x32)
        const int i = t >> 5, f = t & 31;
        float s = 0.f;
        #pragma unroll
        for (int k = 0; k < 4; ++k) s = fmaf(agg[i][k], W1[k * 32 + f], s);
        h1s[i][f] = fmaxf(fmaf(nrm[i], s, b1[f]), 0.f);
    }
    __syncthreads();

    for (int t = tid; t < NN * 32; t += 256) {   // agg2 (16x32)
        const int i = t >> 5, k = t & 31;
        float s = 0.f;
        for (int j = 0; j < NN; ++j) s = fmaf(A[i][j] * nrm[j], h1s[j][k], s);
        agg[i][k] = s;
    }
    __syncthreads();

    {   // h2 + FC, i-range split across 2 half-blocks
        const int f = tid & 127, half = tid >> 7;
        float g = 0.f;
        const float bf = b2[f];
        for (int i = half * 8; i < half * 8 + 8; ++i) {
            float s = 0.f;
            #pragma unroll
            for (int k = 0; k < 32; ++k) s = fmaf(agg[i][k], W2[k * COUT + f], s);
            g = fmaf(fcw[i], fmaxf(fmaf(nrm[i], s, bf), 0.f), g);
        }
        gpart[half][f] = g;
    }
    __syncthreads();
    if (tid < COUT) Gs[tid] = gpart[0][tid] + gpart[1][tid] + fcb[0];
    __syncthreads();

    // ---- Phase B: rolling register pipeline over the contiguous window ----
    #pragma unroll
    for (int j = 0; j < JPT; ++j) {
        if (j + PREF < JPT) r[j + PREF] = bf4[w0 + (j + PREF) * 256 + tid];
        const int t = w0 + j * 256 + tid;
        const float g = Gs[t / (HW2 / 4)];   // 784 float4 per (b,c) plane
        ob4[t] = make_float4(r[j].x * g, r[j].y * g, r[j].z * g, r[j].w * g);
    }
}

extern "C" void kernel_launch(void* const* d_in, const int* in_sizes, int n_in,
                              void* d_out, int out_size, void* d_ws, size_t ws_size,
                              hipStream_t stream)
{
    const float* Bfor  = (const float*)d_in[0];
    const float* Bfon  = (const float*)d_in[1];
    const int*   seg   = (const int*)d_in[2];
    const int*   src   = (const int*)d_in[3];
    const int*   dst   = (const int*)d_in[4];
    const float* convw = (const float*)d_in[5];
    const float* convb = (const float*)d_in[6];
    const float* W1    = (const float*)d_in[7];
    const float* b1    = (const float*)d_in[8];
    const float* W2    = (const float*)d_in[9];
    const float* b2    = (const float*)d_in[10];
    const float* fcw   = (const float*)d_in[11];
    const float* fcb   = (const float*)d_in[12];

    float* part = (float*)d_ws;           // BB*BPI*NN*4 floats = 401 KB
    float* out  = (float*)d_out;

    k_conv_seg<<<BB * BPI, 256, 0, stream>>>(Bfor, seg, convw, part);
    k_graph_scale<<<BB * SBPB, 256, 0, stream>>>(part, src, dst, convb,
                                                 W1, b1, W2, b2, fcw, fcb,
                                                 Bfon, out);
}